// Round 3
// baseline (1991.642 us; speedup 1.0000x reference)
//
#include <hip/hip_runtime.h>
#include <math.h>

#define B_ 64
#define T_ 1024
#define I_ 128
#define H_ 512

typedef _Float16 h2_t __attribute__((ext_vector_type(2)));
union U32H2 { unsigned u; h2_t h; };

__device__ __forceinline__ float fdot2u(unsigned a, unsigned b, float c) {
    U32H2 ua, ub; ua.u = a; ub.u = b;
    return __builtin_amdgcn_fdot2(ua.h, ub.h, c, false);
}
__device__ __forceinline__ unsigned packh2(float x, float y) {
    U32H2 r; r.h.x = (_Float16)x; r.h.y = (_Float16)y; return r.u;
}

// ---------------- prep: pack fp16 weight layouts ----------------
// Thread map in rnn: tid -> w=tid>>6, l=tid&63, c=l&3 (k-slice), g=l>>2.
// Outputs j = w*64 + g*4 + r (r=0..3); k-words (h2 idx) = 64c + m, m=0..63.
// wpack[(r*48+m)*512 + tid] = half2 W[j][2*(64c+m) .. +1]   (m=0..47, reg part)
// wldsg[(slot*512+tid)*4+r] = same for m=48+slot (slot=0..15, LDS part)
__global__ void prep(const float* __restrict__ wih, const float* __restrict__ whh,
                     const float* __restrict__ bih, const float* __restrict__ bhh,
                     unsigned* __restrict__ wpack, unsigned* __restrict__ wldsg,
                     unsigned* __restrict__ wih2, float* __restrict__ biasv) {
    int e = blockIdx.x * 256 + threadIdx.x;
    if (e < 512 * 192) {
        int idx = e >> 9, tid = e & 511;
        int r = idx / 48, m = idx % 48;
        int w = tid >> 6, l = tid & 63, c = l & 3, g = l >> 2;
        int j = w * 64 + g * 4 + r;
        int word = 64 * c + m;
        wpack[e] = packh2(whh[j * H_ + 2 * word], whh[j * H_ + 2 * word + 1]);
    }
    if (e < 32768) {
        int r = e & 3, tid = (e >> 2) & 511, slot = e >> 11;
        int w = tid >> 6, l = tid & 63, c = l & 3, g = l >> 2;
        int j = w * 64 + g * 4 + r;
        int word = 64 * c + 48 + slot;
        wldsg[e] = packh2(whh[j * H_ + 2 * word], whh[j * H_ + 2 * word + 1]);
    }
    if (e < 64 * 512) {
        int i2 = e >> 9, h = e & 511;
        wih2[e] = packh2(wih[h * I_ + 2 * i2], wih[h * I_ + 2 * i2 + 1]);
    }
    if (e < H_) biasv[e] = bih[e] + bhh[e];
}

// ---------------- xp = x @ W_ih^T + biases, fp16 [B][T][H] ----------------
__global__ __launch_bounds__(512, 2) void xp_gemm(
    const float* __restrict__ x, const unsigned* __restrict__ wih2,
    const float* __restrict__ biasv, _Float16* __restrict__ xph) {
    __shared__ unsigned w2[64 * 512];
    __shared__ unsigned x2[32 * 64];
    const int tid = threadIdx.x, b = blockIdx.x, t0 = blockIdx.y * 32;

    #pragma unroll
    for (int q = 0; q < 64; ++q) w2[tid + (q << 9)] = wih2[tid + (q << 9)];
    #pragma unroll
    for (int q = 0; q < 4; ++q) {
        int idx = tid * 4 + q;
        int t = idx >> 6, i2 = idx & 63;
        const float2 xv = *(const float2*)(x + ((size_t)b * T_ + t0 + t) * I_ + (i2 << 1));
        x2[idx] = packh2(xv.x, xv.y);
    }
    __syncthreads();
    const float bias = biasv[tid];
    for (int t = 0; t < 32; ++t) {
        float acc = bias;
        #pragma unroll
        for (int i2 = 0; i2 < 64; ++i2)
            acc = fdot2u(x2[(t << 6) + i2], w2[(i2 << 9) + tid], acc);
        xph[((size_t)b * T_ + t0 + t) * H_ + tid] = (_Float16)acc;
    }
}

// ---------------- serial recurrence: one WG per batch chain ----------------
// 512 thr: quad-local k-partials (c=l&3), shfl_xor reduce, 1 barrier/step.
// h double-buffered in LDS, slice-padded stride 72 -> conflict-free reads.
__global__ __launch_bounds__(512, 2) void rnn_fused(
    const unsigned* __restrict__ xp2,    // [B][T][256] half2 words
    const unsigned* __restrict__ wpack,
    const unsigned* __restrict__ wldsg,
    const float* __restrict__ fcw, const float* __restrict__ fcb,
    float* __restrict__ out)
{
    __shared__ unsigned wlds[32768];     // 128 KB weights (LDS part)
    __shared__ unsigned hbuf[576];       // 2 x (4 slices x 72 words)
    __shared__ float wsum[8];

    const int tid = threadIdx.x;
    const int b = blockIdx.x;
    const int w = tid >> 6, l = tid & 63;
    const int c = l & 3, g = l >> 2;

    {   // stage LDS weights (coalesced uint4)
        const uint4* src = (const uint4*)wldsg;
        uint4* dst = (uint4*)wlds;
        #pragma unroll
        for (int q = 0; q < 16; ++q) dst[q * 512 + tid] = src[q * 512 + tid];
    }
    unsigned wreg[4][48];                // 192 packed half2 (VGPR/AGPR)
    #pragma unroll
    for (int r = 0; r < 4; ++r)
        #pragma unroll
        for (int m = 0; m < 48; ++m)
            wreg[r][m] = wpack[(r * 48 + m) * 512 + tid];

    for (int i = tid; i < 576; i += 512) hbuf[i] = 0u;
    __syncthreads();

    const unsigned* xpb = xp2 + (size_t)b * T_ * 256;
    const uint4* wq = ((const uint4*)wlds) + tid;
    const int W0 = w * 32 + g * 2;                       // h2-word base of outputs
    const int wrbase = 72 * (w >> 1) + 32 * (w & 1) + 2 * g;  // padded write offset

    for (int t = 0; t < T_; ++t) {
        const int pc = (t & 1) * 288;
        const unsigned* hrd = hbuf + pc + 72 * c;

        uint2 xpw = *(const uint2*)(xpb + t * 256 + W0);   // prefetched, used at tail

        float a0 = 0.f, a1 = 0.f, a2 = 0.f, a3 = 0.f;
        #pragma unroll
        for (int m = 0; m < 48; ++m) {
            unsigned hh = hrd[m];                 // ds_read, imm offset, 4-bank spread
            a0 = fdot2u(wreg[0][m], hh, a0);
            a1 = fdot2u(wreg[1][m], hh, a1);
            a2 = fdot2u(wreg[2][m], hh, a2);
            a3 = fdot2u(wreg[3][m], hh, a3);
        }
        #pragma unroll
        for (int s = 0; s < 16; ++s) {
            unsigned hh = hrd[48 + s];
            uint4 w4 = wq[s * 512];               // coalesced b128
            a0 = fdot2u(w4.x, hh, a0);
            a1 = fdot2u(w4.y, hh, a1);
            a2 = fdot2u(w4.z, hh, a2);
            a3 = fdot2u(w4.w, hh, a3);
        }
        // in-quad reduce over k-slices (DPP, no LDS, no barrier)
        a0 += __shfl_xor(a0, 1); a0 += __shfl_xor(a0, 2);
        a1 += __shfl_xor(a1, 1); a1 += __shfl_xor(a1, 2);
        a2 += __shfl_xor(a2, 1); a2 += __shfl_xor(a2, 2);
        a3 += __shfl_xor(a3, 1); a3 += __shfl_xor(a3, 2);

        if (c == 0) {                             // 16 lanes/wave finish 4 outputs
            U32H2 x0, x1; x0.u = xpw.x; x1.u = xpw.y;
            float p0 = (float)x0.h.x + a0;
            float p1 = (float)x0.h.y + a1;
            float p2 = (float)x1.h.x + a2;
            float p3 = (float)x1.h.y + a3;
            float e0 = __expf(2.f * p0), e1 = __expf(2.f * p1);
            float e2 = __expf(2.f * p2), e3 = __expf(2.f * p3);
            float h0 = 1.f - 2.f / (e0 + 1.f), h1 = 1.f - 2.f / (e1 + 1.f);
            float h2v = 1.f - 2.f / (e2 + 1.f), h3 = 1.f - 2.f / (e3 + 1.f);
            uint2 hw; hw.x = packh2(h0, h1); hw.y = packh2(h2v, h3);
            *(uint2*)(hbuf + (pc ^ 288) + wrbase) = hw;   // conflict-free b64
        }
        __syncthreads();                          // single barrier per step
    }

    // head: final h landed in parity-0 buffer
    float p = 0.f;
    if (tid < 256) {
        U32H2 hu; hu.u = hbuf[72 * (tid >> 6) + (tid & 63)];
        p = (float)hu.h.x * fcw[2 * tid] + (float)hu.h.y * fcw[2 * tid + 1];
    }
    #pragma unroll
    for (int off = 32; off >= 1; off >>= 1) p += __shfl_down(p, off, 64);
    if ((tid & 63) == 0 && tid < 256) wsum[tid >> 6] = p;
    __syncthreads();
    if (tid == 0) out[b] = wsum[0] + wsum[1] + wsum[2] + wsum[3] + fcb[0];
}

extern "C" void kernel_launch(void* const* d_in, const int* in_sizes, int n_in,
                              void* d_out, int out_size, void* d_ws, size_t ws_size,
                              hipStream_t stream) {
    const float* x   = (const float*)d_in[0];
    const float* wih = (const float*)d_in[1];
    const float* whh = (const float*)d_in[2];
    const float* bih = (const float*)d_in[3];
    const float* bhh = (const float*)d_in[4];
    const float* fcw = (const float*)d_in[5];
    const float* fcb = (const float*)d_in[6];
    float* out = (float*)d_out;

    // workspace (u32 units): xp2 | wpack | wldsg | wih2 | biasv  (~64.6 MiB)
    unsigned* xp2   = (unsigned*)d_ws;            // 64*1024*256
    unsigned* wpack = xp2 + 16777216;             // 98,304
    unsigned* wldsg = wpack + 98304;              // 32,768
    unsigned* wih2  = wldsg + 32768;              // 32,768
    float*    biasv = (float*)(wih2 + 32768);     // 512

    hipLaunchKernelGGL(prep, dim3(384), dim3(256), 0, stream,
                       wih, whh, bih, bhh, wpack, wldsg, wih2, biasv);
    hipLaunchKernelGGL(xp_gemm, dim3(B_, 32), dim3(512), 0, stream,
                       x, wih2, biasv, (_Float16*)xp2);
    hipLaunchKernelGGL(rnn_fused, dim3(B_), dim3(512), 0, stream,
                       xp2, wpack, wldsg, fcw, fcb, out);
}

// Round 4
// 1631.381 us; speedup vs baseline: 1.2208x; 1.2208x over previous
//
#include <hip/hip_runtime.h>
#include <math.h>

#define B_ 64
#define T_ 1024
#define I_ 128
#define H_ 512

typedef _Float16 h2_t __attribute__((ext_vector_type(2)));
union U32H2 { unsigned u; h2_t h; };

__device__ __forceinline__ float fdot2u(unsigned a, unsigned b, float c) {
    U32H2 ua, ub; ua.u = a; ub.u = b;
    return __builtin_amdgcn_fdot2(ua.h, ub.h, c, false);
}
__device__ __forceinline__ unsigned packh2(float x, float y) {
    U32H2 r; r.h.x = (_Float16)x; r.h.y = (_Float16)y; return r.u;
}

// ---------------- prep: pack fp16 weight layouts (identical to R2) ------------
// rnn thread map: c=tid>>7 (k-slice), g=tid&127 (output quad 4g..4g+3).
// wpack[tid*192 + j*48 + kk2] = half2 W[4g+j][c*128+2kk2 .. +1]   (reg part)
// wldsg[((c*16+m)<<9)+col]    = half2 W[col][c*128+96+2m .. +1]   (LDS part)
// wih2[(i2<<9)+h]             = half2 Wih[h][2i2 .. +1]
__global__ void prep(const float* __restrict__ wih, const float* __restrict__ whh,
                     const float* __restrict__ bih, const float* __restrict__ bhh,
                     unsigned* __restrict__ wpack, unsigned* __restrict__ wldsg,
                     unsigned* __restrict__ wih2, float* __restrict__ biasv) {
    int e = blockIdx.x * 256 + threadIdx.x;
    if (e < 512 * 192) {
        int tid = e / 192, r = e % 192;
        int j = r / 48, kk2 = r % 48;
        int c = tid >> 7, g = tid & 127;
        int row = (g << 2) + j;
        int col = (c << 7) + (kk2 << 1);
        wpack[e] = packh2(whh[row * H_ + col], whh[row * H_ + col + 1]);
    }
    if (e < 4 * 16 * 512) {
        int c = e >> 13, m = (e >> 9) & 15, col = e & 511;
        int k = (c << 7) + 96 + (m << 1);
        wldsg[e] = packh2(whh[col * H_ + k], whh[col * H_ + k + 1]);
    }
    if (e < 64 * 512) {
        int i2 = e >> 9, h = e & 511;
        wih2[e] = packh2(wih[h * I_ + (i2 << 1)], wih[h * I_ + (i2 << 1) + 1]);
    }
    if (e < H_) biasv[e] = bih[e] + bhh[e];
}

// ---------------- xp = x @ W_ih^T + biases, fp16 [B][T][H] (identical to R2) --
__global__ __launch_bounds__(512, 2) void xp_gemm(
    const float* __restrict__ x, const unsigned* __restrict__ wih2,
    const float* __restrict__ biasv, _Float16* __restrict__ xph) {
    __shared__ unsigned w2[64 * 512];
    __shared__ unsigned x2[32 * 64];
    const int tid = threadIdx.x, b = blockIdx.x, t0 = blockIdx.y * 32;

    #pragma unroll
    for (int q = 0; q < 64; ++q) w2[tid + (q << 9)] = wih2[tid + (q << 9)];
    #pragma unroll
    for (int q = 0; q < 4; ++q) {
        int idx = tid * 4 + q;
        int t = idx >> 6, i2 = idx & 63;
        const float2 xv = *(const float2*)(x + ((size_t)b * T_ + t0 + t) * I_ + (i2 << 1));
        x2[idx] = packh2(xv.x, xv.y);
    }
    __syncthreads();
    const float bias = biasv[tid];
    for (int t = 0; t < 32; ++t) {
        float acc = bias;
        #pragma unroll
        for (int i2 = 0; i2 < 64; ++i2)
            acc = fdot2u(x2[(t << 6) + i2], w2[(i2 << 9) + tid], acc);
        xph[((size_t)b * T_ + t0 + t) * H_ + tid] = (_Float16)acc;
    }
}

// ---------------- serial recurrence: one WG per batch chain -------------------
// R2 structure (2 barriers/step, cross-c LDS reduce) with:
//  - uniform uint4 h-reads (16 b128 vs 64 b32)
//  - __launch_bounds__(512) -> up to 256 VGPR, wreg in true VGPRs
//  - xp prefetched one full step ahead
__global__ __launch_bounds__(512) void rnn_fused(
    const unsigned* __restrict__ xp2,    // [B][T][256] half2 words
    const unsigned* __restrict__ wpack,
    const unsigned* __restrict__ wldsg,
    const float* __restrict__ fcw, const float* __restrict__ fcb,
    float* __restrict__ out)
{
    __shared__ __align__(16) unsigned wlds[4 * 16 * 512];  // 128 KB
    __shared__ __align__(16) float part[4 * 512];          // 8 KB
    __shared__ __align__(16) unsigned h2buf[256];          // 1 KB
    __shared__ float wsum[4];

    const int tid = threadIdx.x;
    const int b = blockIdx.x;
    const int c = tid >> 7, g = tid & 127;

    {   // stage LDS weights (coalesced uint4)
        const uint4* src = (const uint4*)wldsg;
        uint4* dst = (uint4*)wlds;
        #pragma unroll
        for (int q = 0; q < 16; ++q) dst[tid + (q << 9)] = src[tid + (q << 9)];
    }
    unsigned wreg[4][48];                    // 192 packed half2 words
    {
        const unsigned* wp = wpack + tid * 192;
        #pragma unroll
        for (int j = 0; j < 4; ++j)
            #pragma unroll
            for (int kk2 = 0; kk2 < 48; ++kk2)
                wreg[j][kk2] = wp[j * 48 + kk2];
    }
    if (tid < 256) h2buf[tid] = 0u;
    __syncthreads();

    const unsigned* xpb = xp2 + (size_t)b * T_ * 256;
    const uint4* wq = ((const uint4*)wlds) + (c << 11) + g;  // + m*128, imm-offset safe
    const uint4* hv = ((const uint4*)h2buf) + (c << 4);      // wave-uniform base
    float4* part4w = ((float4*)part) + (c << 7) + g;
    const float2* p2 = (const float2*)part;

    unsigned xpw = (tid < 256) ? xpb[tid] : 0u;              // xp[0]

    for (int t = 0; t < T_; ++t) {
        // prefetch xp[t+1] (consumed at the END of the NEXT iteration's tail)
        unsigned xpn = 0u;
        if (tid < 256 && t + 1 < T_) xpn = xpb[(t + 1) * 256 + tid];

        float a0 = 0.f, a1 = 0.f, a2 = 0.f, a3 = 0.f;
        // register-resident weights: 12 uniform b128 h-reads, 192 fdot2
        #pragma unroll
        for (int q = 0; q < 12; ++q) {
            const uint4 hh = hv[q];
            const int m = q << 2;
            a0 = fdot2u(wreg[0][m+0], hh.x, a0); a1 = fdot2u(wreg[1][m+0], hh.x, a1);
            a2 = fdot2u(wreg[2][m+0], hh.x, a2); a3 = fdot2u(wreg[3][m+0], hh.x, a3);
            a0 = fdot2u(wreg[0][m+1], hh.y, a0); a1 = fdot2u(wreg[1][m+1], hh.y, a1);
            a2 = fdot2u(wreg[2][m+1], hh.y, a2); a3 = fdot2u(wreg[3][m+1], hh.y, a3);
            a0 = fdot2u(wreg[0][m+2], hh.z, a0); a1 = fdot2u(wreg[1][m+2], hh.z, a1);
            a2 = fdot2u(wreg[2][m+2], hh.z, a2); a3 = fdot2u(wreg[3][m+2], hh.z, a3);
            a0 = fdot2u(wreg[0][m+3], hh.w, a0); a1 = fdot2u(wreg[1][m+3], hh.w, a1);
            a2 = fdot2u(wreg[2][m+3], hh.w, a2); a3 = fdot2u(wreg[3][m+3], hh.w, a3);
        }
        // LDS-resident weights: 4 uniform b128 h-reads + 16 coalesced b128 w-reads
        #pragma unroll
        for (int q = 0; q < 4; ++q) {
            const uint4 hh = hv[12 + q];
            const uint4 w0 = wq[(q * 4 + 0) * 128];
            const uint4 w1 = wq[(q * 4 + 1) * 128];
            const uint4 w2v = wq[(q * 4 + 2) * 128];
            const uint4 w3 = wq[(q * 4 + 3) * 128];
            a0 = fdot2u(w0.x, hh.x, a0); a1 = fdot2u(w0.y, hh.x, a1);
            a2 = fdot2u(w0.z, hh.x, a2); a3 = fdot2u(w0.w, hh.x, a3);
            a0 = fdot2u(w1.x, hh.y, a0); a1 = fdot2u(w1.y, hh.y, a1);
            a2 = fdot2u(w1.z, hh.y, a2); a3 = fdot2u(w1.w, hh.y, a3);
            a0 = fdot2u(w2v.x, hh.z, a0); a1 = fdot2u(w2v.y, hh.z, a1);
            a2 = fdot2u(w2v.z, hh.z, a2); a3 = fdot2u(w2v.w, hh.z, a3);
            a0 = fdot2u(w3.x, hh.w, a0); a1 = fdot2u(w3.y, hh.w, a1);
            a2 = fdot2u(w3.z, hh.w, a2); a3 = fdot2u(w3.w, hh.w, a3);
        }
        *part4w = make_float4(a0, a1, a2, a3);
        __syncthreads();                         // part ready

        if (tid < 256) {                         // cross-c reduce + tanh (4 waves)
            float2 s0 = p2[tid];
            float2 s1 = p2[256 + tid];
            float2 s2 = p2[512 + tid];
            float2 s3 = p2[768 + tid];
            U32H2 xu; xu.u = xpw;
            float pre0 = (float)xu.h.x + s0.x + s1.x + s2.x + s3.x;
            float pre1 = (float)xu.h.y + s0.y + s1.y + s2.y + s3.y;
            float e0 = __expf(2.0f * pre0), e1 = __expf(2.0f * pre1);
            float h0 = 1.0f - 2.0f / (e0 + 1.0f);
            float h1 = 1.0f - 2.0f / (e1 + 1.0f);
            h2buf[tid] = packh2(h0, h1);
        }
        xpw = xpn;
        __syncthreads();                         // h ready
    }

    // head: out[b] = dot(h, fc_w) + fc_b
    float p = 0.f;
    if (tid < 256) {
        U32H2 hu; hu.u = h2buf[tid];
        p = (float)hu.h.x * fcw[tid << 1] + (float)hu.h.y * fcw[(tid << 1) + 1];
    }
    #pragma unroll
    for (int off = 32; off >= 1; off >>= 1) p += __shfl_down(p, off, 64);
    if ((tid & 63) == 0 && tid < 256) wsum[tid >> 6] = p;
    __syncthreads();
    if (tid == 0) out[b] = wsum[0] + wsum[1] + wsum[2] + wsum[3] + fcb[0];
}

extern "C" void kernel_launch(void* const* d_in, const int* in_sizes, int n_in,
                              void* d_out, int out_size, void* d_ws, size_t ws_size,
                              hipStream_t stream) {
    const float* x   = (const float*)d_in[0];
    const float* wih = (const float*)d_in[1];
    const float* whh = (const float*)d_in[2];
    const float* bih = (const float*)d_in[3];
    const float* bhh = (const float*)d_in[4];
    const float* fcw = (const float*)d_in[5];
    const float* fcb = (const float*)d_in[6];
    float* out = (float*)d_out;

    // workspace (u32 units): xp2 | wpack | wldsg | wih2 | biasv  (~64.6 MiB)
    unsigned* xp2   = (unsigned*)d_ws;            // 64*1024*256
    unsigned* wpack = xp2 + 16777216;             // 98,304
    unsigned* wldsg = wpack + 98304;              // 32,768
    unsigned* wih2  = wldsg + 32768;              // 32,768
    float*    biasv = (float*)(wih2 + 32768);     // 512

    hipLaunchKernelGGL(prep, dim3(384), dim3(256), 0, stream,
                       wih, whh, bih, bhh, wpack, wldsg, wih2, biasv);
    hipLaunchKernelGGL(xp_gemm, dim3(B_, 32), dim3(512), 0, stream,
                       x, wih2, biasv, (_Float16*)xp2);
    hipLaunchKernelGGL(rnn_fused, dim3(B_), dim3(512), 0, stream,
                       xp2, wpack, wldsg, fcw, fcb, out);
}